// Round 12
// baseline (16.910 us; speedup 1.0000x reference)
//
#include <hip/hip_runtime.h>

#define NQ 12
#define DIM 4096
#define BLK 256

typedef float v2f __attribute__((ext_vector_type(2)));

// gray-to-binary (== CNOT chain relabel): bit i of result = XOR of bits >= i.
__host__ __device__ constexpr int igrayc(int v) {
    v ^= v >> 1; v ^= v >> 2; v ^= v >> 4; v ^= v >> 8;
    return v & (DIM - 1);
}
// binary-to-gray composed k times: g^1=v^(v>>1), g^2=v^(v>>2), g^3=g^1∘g^2
__host__ __device__ constexpr int gkf(int v, int k) {
    if (k == 1) v ^= v >> 1;
    else if (k == 2) v ^= v >> 2;
    else { v ^= v >> 2; v ^= v >> 1; }
    return v;
}
// LDS swizzle (involution); bank-pair = low4(slot).
__host__ __device__ constexpr int sigf(int v) { return v ^ ((v >> 4) & 15); }
// slot of logical label n at epoch k: slot = sig(gray^k(n))
__host__ __device__ constexpr int TkF(int v, int k) { return sigf(gkf(v, k)); }

// C1 register-dir slot masks: j0->0x188 (σγe8), j1->0x300 (σγe9),
// j2->0x600 (σγe10), j3->0xC00 (σγe11)
__host__ __device__ constexpr int c1off(int j) {
    return ((j & 1) ? 0x188 : 0) ^ ((j & 2) ? 0x300 : 0)
         ^ ((j & 4) ? 0x600 : 0) ^ ((j & 8) ? 0xC00 : 0);
}

__device__ __forceinline__ v2f cmul(v2f a, v2f b) {
    v2f r; r.x = a.x * b.x - a.y * b.y; r.y = a.x * b.y + a.y * b.x; return r;
}
// RY pair, packed f32: first arg is side0 (label bit = 0)
__device__ __forceinline__ void gate_pair(v2f& a0, v2f& a1, v2f cc, v2f ss, v2f ns) {
    v2f t0 = a0, t1 = a1;
    a0 = __builtin_elementwise_fma(ns, t1, cc * t0);   // c*a0 - s*a1
    a1 = __builtin_elementwise_fma(ss, t0, cc * t1);   // s*a0 + c*a1
}
template<int PB>
__device__ __forceinline__ void gate16(v2f (&a)[16], float c, float s) {
    const v2f cc = {c, c}, ss = {s, s}, ns = {-s, -s};
    #pragma unroll
    for (int j0 = 0; j0 < 16; ++j0) {
        if (j0 & PB) continue;
        gate_pair(a[j0], a[j0 | PB], cc, ss, ns);
    }
}

// RY paired ACROSS LANES via DPP; BETA = hosted label bit (side from lb).
template<int CTRL, int BETA>
__device__ __forceinline__ void dpp_gate16(v2f (&a)[16], float c, float s, int lb) {
    const float sl = ((lb >> BETA) & 1) ? s : -s;
    const v2f cc = {c, c}, sv = {sl, sl};
    #pragma unroll
    for (int j = 0; j < 16; ++j) {
        int bx = __builtin_amdgcn_update_dpp(0, __float_as_int(a[j].x), CTRL, 0xf, 0xf, true);
        int by = __builtin_amdgcn_update_dpp(0, __float_as_int(a[j].y), CTRL, 0xf, 0xf, true);
        v2f b; b.x = __int_as_float(bx); b.y = __int_as_float(by);
        a[j] = __builtin_elementwise_fma(sv, b, cc * a[j]);
    }
}
#define DPP_XOR1  0xB1   // quad_perm [1,0,3,2]
#define DPP_XOR2  0x4E   // quad_perm [2,3,0,1]
#define DPP_XOR7  0x141  // row_half_mirror
#define DPP_XOR15 0x140  // row_mirror

template<int K, int OSH>
__device__ __forceinline__ void ld16(const char* bufc, int sb8, v2f (&a)[16]) {
    #pragma unroll
    for (int j = 0; j < 16; ++j)
        a[j] = *(const v2f*)(bufc + (sb8 ^ (TkF(j << OSH, K) << 3)));
}
template<int K, int OSH>
__device__ __forceinline__ void st16(char* bufc, int sb8, const v2f (&a)[16]) {
    #pragma unroll
    for (int j = 0; j < 16; ++j)
        *(v2f*)(bufc + (sb8 ^ (TkF(j << OSH, K) << 3))) = a[j];
}

// wave64 sum on the VALU pipe (DPP row ops), result valid in lane 63
__device__ __forceinline__ float wave64_sum(float v) {
    v += __int_as_float(__builtin_amdgcn_update_dpp(0, __float_as_int(v), 0x111, 0xf, 0xf, true));
    v += __int_as_float(__builtin_amdgcn_update_dpp(0, __float_as_int(v), 0x112, 0xf, 0xf, true));
    v += __int_as_float(__builtin_amdgcn_update_dpp(0, __float_as_int(v), 0x114, 0xf, 0xf, true));
    v += __int_as_float(__builtin_amdgcn_update_dpp(0, __float_as_int(v), 0x118, 0xf, 0xf, true));
    v += __int_as_float(__builtin_amdgcn_update_dpp(0, __float_as_int(v), 0x142, 0xa, 0xf, false));
    v += __int_as_float(__builtin_amdgcn_update_dpp(0, __float_as_int(v), 0x143, 0xc, 0xf, false));
    return v;
}

__global__ __launch_bounds__(BLK, 2)
void qsim_kernel(const float* __restrict__ x,
                 const float* __restrict__ rys,
                 float* __restrict__ out) {
    __shared__ __align__(16) v2f buf[DIM];           // 32 KB, slot = sig(m) forever
    __shared__ float cr[4 * NQ], sr[4 * NQ];
    __shared__ v2f fac[NQ][2];                       // init factors (d0 RY absorbed)
    __shared__ float zred[4][NQ];

    const int b = blockIdx.x;
    const int t = threadIdx.x;                       // 8 bits
    char* bufc = (char*)buf;

    if (t < 4 * NQ) {
        float th = 0.5f * rys[t];
        cr[t] = cosf(th); sr[t] = sinf(th);
    }
    if (t >= 64 && t < 64 + NQ) {
        int q = t - 64;
        float xh = 0.5f * x[b * NQ + q];
        float cx = cosf(xh), sx = sinf(xh);
        float th = 0.5f * rys[q];                    // layer-0 RY absorbed
        float c0 = cosf(th), s0 = sinf(th);
        int p = NQ - 1 - q;                          // bit position of qubit q
        fac[p][0] = v2f{c0 * cx,  s0 * sx};          // (RY·RX)|0>, bit=0
        fac[p][1] = v2f{s0 * cx, -c0 * sx};          // bit=1
    }
    __syncthreads();

    // AB lane base: DPP masks {1,2,7,15}->label bits e0..e3; t4,t5->e8,e9;
    // t6,t7->e10,e11. (verified rank-4 bank spread for K=1,2,3)
    const int lb = (t & 3) ^ (((t >> 2) & 1) * 7) ^ (((t >> 3) & 1) * 12)
                 ^ ((t >> 4) << 8);

    // ==== P0': build product state directly in lb embedding + L1 dirs 0-7 ====
    // n = lb(t) ^ (j<<4); m = gray(n):
    //   m0=t0^t1 m1=t1^t3 m2=t2 m3=t3^j0 m4=j0^j1 m5=j1^j2 m6=j2^j3
    //   m7=j3^t4 m8=t4^t5 m9=t5^t6 m10=t6^t7 m11=t7
    {
        const int m0 = (t ^ (t >> 1)) & 1;
        const int m1 = ((t >> 1) ^ (t >> 3)) & 1;
        const int m2 = (t >> 2) & 1;
        const int t3b = (t >> 3) & 1, t4b = (t >> 4) & 1;
        const int m8 = ((t >> 4) ^ (t >> 5)) & 1;
        const int m9 = ((t >> 5) ^ (t >> 6)) & 1;
        const int m10 = ((t >> 6) ^ (t >> 7)) & 1;
        const int m11 = (t >> 7) & 1;
        v2f U = cmul(cmul(cmul(fac[0][m0], fac[1][m1]), cmul(fac[2][m2], fac[8][m8])),
                     cmul(cmul(fac[9][m9], fac[10][m10]), fac[11][m11]));
        v2f f3[2] = {fac[3][t3b], fac[3][t3b ^ 1]};  // index j0
        v2f f4[2] = {fac[4][0], fac[4][1]};          // index j0^j1
        v2f f5[2] = {fac[5][0], fac[5][1]};          // index j1^j2
        v2f f6[2] = {fac[6][0], fac[6][1]};          // index j2^j3
        v2f f7[2] = {fac[7][t4b], fac[7][t4b ^ 1]};  // index j3

        v2f T7[2], T6[4], T5[8], a[16];
        #pragma unroll
        for (int j3 = 0; j3 < 2; ++j3) T7[j3] = cmul(U, f7[j3]);
        #pragma unroll
        for (int h = 0; h < 4; ++h) {                // h = (j3<<1)|j2
            int j2 = h & 1, j3 = h >> 1;
            T6[h] = cmul(T7[j3], f6[j2 ^ j3]);
        }
        #pragma unroll
        for (int h = 0; h < 8; ++h) {                // h = (j3<<2)|(j2<<1)|j1
            int j1 = h & 1, j2 = (h >> 1) & 1;
            T5[h] = cmul(T6[h >> 1], f5[j1 ^ j2]);
        }
        #pragma unroll
        for (int j = 0; j < 16; ++j) {
            int j0 = j & 1, j1 = (j >> 1) & 1;
            v2f A = cmul(T5[j >> 1], f4[j0 ^ j1]);
            a[j] = cmul(A, f3[j0]);
        }
        gate16<1>(a, cr[19], sr[19]);                // L1 dir4 (q7)
        gate16<2>(a, cr[18], sr[18]);                // q6
        gate16<4>(a, cr[17], sr[17]);                // q5
        gate16<8>(a, cr[16], sr[16]);                // q4
        dpp_gate16<DPP_XOR1,  0>(a, cr[23], sr[23], lb);  // q11
        dpp_gate16<DPP_XOR2,  1>(a, cr[22], sr[22], lb);  // q10
        dpp_gate16<DPP_XOR7,  2>(a, cr[21], sr[21], lb);  // q9
        dpp_gate16<DPP_XOR15, 3>(a, cr[20], sr[20], lb);  // q8
        st16<1, 4>(bufc, TkF(lb, 1) << 3, a);
    }
    __syncthreads();

    // ==== C1: L1 dirs 8-11 + L2 dirs 8-11, one in-place pass ====
    // slot map: t0->s0 t1->s1 t2->0x147 t3->s3 t4->s4 t5->s5 t6->s6 t7->s7;
    // regs via c1off. Bank low4: s0=t0^t2 s1=t1^t2 s2=t2 s3=t3^j0 (rank 4).
    {
        const int sb8 = ((t & ~4) ^ (((t >> 2) & 1) * 0x147)) << 3;
        v2f a[16];
        #pragma unroll
        for (int j = 0; j < 16; ++j)
            a[j] = *(const v2f*)(bufc + (sb8 ^ (c1off(j) << 3)));

        // L1 d8 (q3, cr[15]): pair (j, j^1); side = t2 ^ j0 -> runtime t2 sign
        {
            float c = cr[15], s = sr[15];
            float swf = ((t >> 2) & 1) ? s : -s;
            v2f cc = {c, c}, sw = {swf, swf}, nsw = {-swf, -swf};
            #pragma unroll
            for (int j = 0; j < 16; j += 2) {
                v2f u = a[j], v = a[j + 1];
                a[j]     = __builtin_elementwise_fma(sw, v, cc * u);
                a[j + 1] = __builtin_elementwise_fma(nsw, u, cc * v);
            }
        }
        gate16<2>(a, cr[14], sr[14]);                // L1 d9 (q2), side=j1
        gate16<4>(a, cr[13], sr[13]);                // L1 d10 (q1), side=j2
        gate16<8>(a, cr[12], sr[12]);                // L1 d11 (q0), side=j3

        // L2 d8 (q3, cr[27]): partner lane^7 (DPP); side = t2 ^ parity(j)
        {
            float c = cr[27], s = sr[27];
            float bs = ((t >> 2) & 1) ? s : -s;
            v2f cc = {c, c};
            #pragma unroll
            for (int j = 0; j < 16; ++j) {
                float slf = (__builtin_popcount(j) & 1) ? -bs : bs;
                v2f sv = {slf, slf};
                int bx = __builtin_amdgcn_update_dpp(0, __float_as_int(a[j].x), DPP_XOR7, 0xf, 0xf, true);
                int by = __builtin_amdgcn_update_dpp(0, __float_as_int(a[j].y), DPP_XOR7, 0xf, 0xf, true);
                v2f p; p.x = __int_as_float(bx); p.y = __int_as_float(by);
                a[j] = __builtin_elementwise_fma(sv, p, cc * a[j]);
            }
        }
        // L2 d9 (q2, cr[26]): reg mask 3, side = j1^j2^j3 (static pair order)
        {
            const v2f cc = {cr[26], cr[26]}, ss = {sr[26], sr[26]}, ns = {-sr[26], -sr[26]};
            gate_pair(a[0], a[3], cc, ss, ns);   gate_pair(a[1], a[2], cc, ss, ns);
            gate_pair(a[7], a[4], cc, ss, ns);   gate_pair(a[6], a[5], cc, ss, ns);
            gate_pair(a[11], a[8], cc, ss, ns);  gate_pair(a[10], a[9], cc, ss, ns);
            gate_pair(a[12], a[15], cc, ss, ns); gate_pair(a[13], a[14], cc, ss, ns);
        }
        // L2 d10 (q1, cr[25]): reg mask 6, side = j2^j3
        {
            const v2f cc = {cr[25], cr[25]}, ss = {sr[25], sr[25]}, ns = {-sr[25], -sr[25]};
            gate_pair(a[0], a[6], cc, ss, ns);   gate_pair(a[1], a[7], cc, ss, ns);
            gate_pair(a[2], a[4], cc, ss, ns);   gate_pair(a[3], a[5], cc, ss, ns);
            gate_pair(a[14], a[8], cc, ss, ns);  gate_pair(a[15], a[9], cc, ss, ns);
            gate_pair(a[12], a[10], cc, ss, ns); gate_pair(a[13], a[11], cc, ss, ns);
        }
        // L2 d11 (q0, cr[24]): reg mask 12, side = j3
        {
            const v2f cc = {cr[24], cr[24]}, ss = {sr[24], sr[24]}, ns = {-sr[24], -sr[24]};
            gate_pair(a[0], a[12], cc, ss, ns);  gate_pair(a[1], a[13], cc, ss, ns);
            gate_pair(a[2], a[14], cc, ss, ns);  gate_pair(a[3], a[15], cc, ss, ns);
            gate_pair(a[4], a[8], cc, ss, ns);   gate_pair(a[5], a[9], cc, ss, ns);
            gate_pair(a[6], a[10], cc, ss, ns);  gate_pair(a[7], a[11], cc, ss, ns);
        }
        #pragma unroll
        for (int j = 0; j < 16; ++j)
            *(v2f*)(bufc + (sb8 ^ (c1off(j) << 3))) = a[j];
    }
    __syncthreads();

    // ==== AB2: L2 dirs 0-7 (reused verbatim from R11) ====
    {
        const int sb8 = TkF(lb, 2) << 3;
        v2f a[16];
        ld16<2, 4>(bufc, sb8, a);
        gate16<1>(a, cr[31], sr[31]);
        gate16<2>(a, cr[30], sr[30]);
        gate16<4>(a, cr[29], sr[29]);
        gate16<8>(a, cr[28], sr[28]);
        dpp_gate16<DPP_XOR1,  0>(a, cr[35], sr[35], lb);
        dpp_gate16<DPP_XOR2,  1>(a, cr[34], sr[34], lb);
        dpp_gate16<DPP_XOR7,  2>(a, cr[33], sr[33], lb);
        dpp_gate16<DPP_XOR15, 3>(a, cr[32], sr[32], lb);
        st16<2, 4>(bufc, sb8, a);
    }
    __syncthreads();

    // ==== C2: relabel3 + L3 dirs 8-11 (reused verbatim from R11) ====
    {
        const int sb8 = TkF(t, 3) << 3;
        v2f a[16];
        ld16<3, 8>(bufc, sb8, a);
        gate16<1>(a, cr[39], sr[39]);
        gate16<2>(a, cr[38], sr[38]);
        gate16<4>(a, cr[37], sr[37]);
        gate16<8>(a, cr[36], sr[36]);
        st16<3, 8>(bufc, sb8, a);
    }
    __syncthreads();

    // ==== P5: L3 dirs 0-7 + relabel4 (labels only) + Z via WHT, no store ====
    {
        const int sb8 = TkF(lb, 3) << 3;
        v2f a[16];
        ld16<3, 4>(bufc, sb8, a);
        gate16<1>(a, cr[43], sr[43]);
        gate16<2>(a, cr[42], sr[42]);
        gate16<4>(a, cr[41], sr[41]);
        gate16<8>(a, cr[40], sr[40]);
        dpp_gate16<DPP_XOR1,  0>(a, cr[47], sr[47], lb);
        dpp_gate16<DPP_XOR2,  1>(a, cr[46], sr[46], lb);
        dpp_gate16<DPP_XOR7,  2>(a, cr[45], sr[45], lb);
        dpp_gate16<DPP_XOR15, 3>(a, cr[44], sr[44], lb);

        float pr[16];
        #pragma unroll
        for (int j = 0; j < 16; ++j)
            pr[j] = a[j].x * a[j].x + a[j].y * a[j].y;
        // WHT over register bits (label dirs e4..e7)
        #pragma unroll
        for (int bit = 1; bit < 16; bit <<= 1) {
            #pragma unroll
            for (int j = 0; j < 16; ++j) {
                if (j & bit) continue;
                float u = pr[j], w = pr[j | bit];
                pr[j] = u + w;
                pr[j | bit] = u - w;
            }
        }
        // label bit l coefficient: l<=4 -> pr[15]; l=5 -> pr[14]; l=6 -> pr[12];
        // l=7 -> pr[8]; l>=8 -> pr[0]
        const int R = igrayc(lb);                    // runtime label base (n4)
        #pragma unroll
        for (int q = 0; q < NQ; ++q) {
            const int l = NQ - 1 - q;
            const float cf = (l <= 4) ? pr[15]
                           : (l == 5) ? pr[14]
                           : (l == 6) ? pr[12]
                           : (l == 7) ? pr[8]  : pr[0];
            float v = ((R >> l) & 1) ? -cf : cf;
            v = wave64_sum(v);
            if ((t & 63) == 63) zred[t >> 6][q] = v;
        }
    }
    __syncthreads();
    if (t < NQ)
        out[b * NQ + t] = zred[0][t] + zred[1][t] + zred[2][t] + zred[3][t];
}

extern "C" void kernel_launch(void* const* d_in, const int* in_sizes, int n_in,
                              void* d_out, int out_size, void* d_ws, size_t ws_size,
                              hipStream_t stream) {
    const float* x   = (const float*)d_in[0];
    const float* rys = (const float*)d_in[1];
    // d_in[2] (cnot_params) unused by the reference — CNOT takes no params.
    float* out = (float*)d_out;
    qsim_kernel<<<512, BLK, 0, stream>>>(x, rys, out);
}